// Round 4
// baseline (595.111 us; speedup 1.0000x reference)
//
#include <hip/hip_runtime.h>
#include <hip/hip_bf16.h>
#include <stdint.h>
#include <stddef.h>

typedef __attribute__((ext_vector_type(4))) float f32x4;
typedef __attribute__((ext_vector_type(8))) short s16x8;

#define BN 128
#define MARGIN 6.0e-4f

// exact RNE f32 -> bf16 bits
__device__ __forceinline__ unsigned short f2bf(float f) {
    unsigned int u = __float_as_uint(f);
    unsigned int r = (u + 0x7fffu + ((u >> 16) & 1u)) >> 16;
    return (unsigned short)r;
}
__device__ __forceinline__ float bf2f(short u) {
    return __uint_as_float(((unsigned int)(unsigned short)u) << 16);
}

// ---------------------------------------------------------------------------
// numpy pairwise sum of squares, n=256, bit-exact emulation.
// np: n=256 -> pw(0:128) + pw(128:256); each 128-block: 8 accumulators,
// combine ((r0+r1)+(r2+r3)) + ((r4+r5)+(r6+r7)).  All ops un-fused f32.
// ---------------------------------------------------------------------------
__device__ float np_pw256_sq(const float* __restrict__ p, int stride) {
    float half[2];
#pragma unroll
    for (int h = 0; h < 2; ++h) {
        const float* q = p + (size_t)(h * 128) * stride;
        float r[8];
#pragma unroll
        for (int j = 0; j < 8; ++j) {
            float v = q[(size_t)j * stride];
            r[j] = __fmul_rn(v, v);
        }
        for (int i = 8; i < 128; i += 8) {
#pragma unroll
            for (int j = 0; j < 8; ++j) {
                float v = q[(size_t)(i + j) * stride];
                r[j] = __fadd_rn(r[j], __fmul_rn(v, v));
            }
        }
        half[h] = __fadd_rn(__fadd_rn(__fadd_rn(r[0], r[1]), __fadd_rn(r[2], r[3])),
                            __fadd_rn(__fadd_rn(r[4], r[5]), __fadd_rn(r[6], r[7])));
    }
    return __fadd_rn(half[0], half[1]);
}

// ---------------------------------------------------------------------------
// emb f32 [1024,256] -> bf16 bits in ws
// ---------------------------------------------------------------------------
__global__ __launch_bounds__(256) void emb2bf16_kernel(const float* __restrict__ emb,
                                                       unsigned short* __restrict__ embb) {
    int i = blockIdx.x * 256 + threadIdx.x;  // 65536 threads
#pragma unroll
    for (int j = 0; j < 4; ++j) {
        int k = i * 4 + j;
        embb[k] = f2bf(emb[k]);
    }
}

// ---------------------------------------------------------------------------
// B-chunk prefetch from bf16 emb copy: [128 codes][32 dims] -> LDS,
// global_load_lds width=16, wave-uniform base + lane*16.
// ---------------------------------------------------------------------------
__device__ __forceinline__ void prefetch_B(const unsigned short* __restrict__ embb,
                                           unsigned short* bbuf, int s, int w, int l) {
    int kt = s >> 3, ds = s & 7;
#pragma unroll
    for (int e = 0; e < 2; ++e) {
        int idx16 = (w * 2 + e) * 64 + l;  // 0..511, lane-contiguous
        int code  = idx16 >> 2;
        int grp   = idx16 & 3;
        const unsigned short* src = embb + (((size_t)(kt * 128 + code)) << 8) + ds * 32 + grp * 8;
        void* dst = (void*)(bbuf + (size_t)idx16 * 8);
        __builtin_amdgcn_global_load_lds((const __attribute__((address_space(1))) void*)src,
                                         (__attribute__((address_space(3))) void*)dst,
                                         16, 0, 0);
    }
}

// ---------------------------------------------------------------------------
// Fused VQ: bf16 MFMA coarse pass (score = enorm - 2*dot, best-2/lane) +
// bit-exact numpy-f32 rescore of near-tie rows.
// ---------------------------------------------------------------------------
__global__ __launch_bounds__(256, 2) void vq_kernel(
        const float* __restrict__ z,
        const float* __restrict__ emb,
        const unsigned short* __restrict__ embb,
        float* __restrict__ out) {

    __shared__ unsigned short A_sh[BN * 256];        // 64 KB, bf16 z tile
    __shared__ unsigned short B_sh[2][BN * 32];      // 16 KB, dbuf emb chunks

    const int t  = threadIdx.x;
    const int w  = t >> 6;
    const int l  = t & 63;
    const int c  = l & 15;   // MFMA N-lane
    const int q  = l >> 4;   // MFMA quad
    const int wr = w >> 1;   // spatial half
    const int wc = w & 1;    // code half

    const int n0    = blockIdx.x * BN;
    const int b_img = n0 >> 12;
    const int hw0   = n0 & 4095;
    const float* zb = z + (size_t)b_img * (256 * 4096) + hw0;

    // ---- Stage A: z NCHW f32 -> bf16 [n][d] transposed, swizzled ----
#pragma unroll 4
    for (int it = 0; it < 16; ++it) {
        int task = it * 256 + t;          // 128 n x 32 dgroups
        int n  = task & 127;              // lane-contiguous -> coalesced
        int dg = task >> 7;
        const float* g = zb + (size_t)(dg * 8) * 4096 + n;
        s16x8 v;
#pragma unroll
        for (int j = 0; j < 8; ++j) v[j] = (short)f2bf(g[(size_t)j * 4096]);
        *(s16x8*)&A_sh[n * 256 + ((dg ^ (n & 7)) * 8)] = v;
    }
    __syncthreads();

    prefetch_B(embb, &B_sh[0][0], 0, w, l);

    f32x4 acc[4][4];
    float en_acc[4];
    float v1[16], v2[16];
    int   i1[16], i2[16];
#pragma unroll
    for (int i = 0; i < 4; ++i)
#pragma unroll
        for (int j = 0; j < 4; ++j) acc[i][j] = (f32x4){0.f, 0.f, 0.f, 0.f};
#pragma unroll
    for (int j = 0; j < 4; ++j) en_acc[j] = 0.f;
#pragma unroll
    for (int p = 0; p < 16; ++p) { v1[p] = 3.4e38f; v2[p] = 3.4e38f; i1[p] = 0x7fffffff; i2[p] = 0x7fffffff; }

    for (int kt = 0; kt < 8; ++kt) {
#pragma unroll
        for (int ds = 0; ds < 8; ++ds) {
            int s = kt * 8 + ds;
            __syncthreads();                                   // drains prefetch(s)
            if (s + 1 < 64) prefetch_B(embb, &B_sh[(s + 1) & 1][0], s + 1, w, l);

            const unsigned short* Bb = &B_sh[s & 1][0];

            s16x8 af[4], bfr[4];
#pragma unroll
            for (int i = 0; i < 4; ++i) {
                int n  = wr * 64 + i * 16 + c;
                int pg = ((ds << 2) + q) ^ (n & 7);
                af[i] = *(const s16x8*)&A_sh[n * 256 + pg * 8];
            }
#pragma unroll
            for (int j = 0; j < 4; ++j) {
                int k = wc * 64 + j * 16 + c;
                bfr[j] = *(const s16x8*)&Bb[k * 32 + q * 8];
            }
            // coarse enorm partials from the loaded B fragments
#pragma unroll
            for (int j = 0; j < 4; ++j) {
                float sj = en_acc[j];
#pragma unroll
                for (int e = 0; e < 8; ++e) { float b = bf2f(bfr[j][e]); sj = fmaf(b, b, sj); }
                en_acc[j] = sj;
            }
#pragma unroll
            for (int i = 0; i < 4; ++i)
#pragma unroll
                for (int j = 0; j < 4; ++j)
                    acc[i][j] = __builtin_amdgcn_mfma_f32_16x16x32_bf16(af[i], bfr[j], acc[i][j], 0, 0, 0);
        }

        // ---- kt epilogue: finish coarse enorm, coarse score, best-2 ----
#pragma unroll
        for (int j = 0; j < 4; ++j) {
            float en = en_acc[j];
            en += __shfl_xor(en, 16, 64);
            en += __shfl_xor(en, 32, 64);
            en_acc[j] = 0.f;
            int code = kt * 128 + wc * 64 + j * 16 + c;
#pragma unroll
            for (int i = 0; i < 4; ++i) {
#pragma unroll
                for (int r = 0; r < 4; ++r) {
                    int p = i * 4 + r;
                    float sc = fmaf(-2.0f, acc[i][j][r], en);
                    if (sc < v1[p]) {
                        v2[p] = v1[p]; i2[p] = i1[p];
                        v1[p] = sc;    i1[p] = code;
                    } else if (sc < v2[p]) {
                        v2[p] = sc;    i2[p] = code;
                    }
                }
            }
        }
#pragma unroll
        for (int i = 0; i < 4; ++i)
#pragma unroll
            for (int j = 0; j < 4; ++j) acc[i][j] = (f32x4){0.f, 0.f, 0.f, 0.f};
    }

    __syncthreads();   // everyone done with A_sh/B_sh -> reuse as scratch

    // ---- dump best-2 per (lane, row) into A_sh alias: [128 rows][64 slots] ----
    float* cv = (float*)A_sh;              // 128*64 f32 = 32 KB
    int*   ci = ((int*)A_sh) + 8192;       // 128*64 i32 = 32 KB
#pragma unroll
    for (int p = 0; p < 16; ++p) {
        int row  = wr * 64 + (p >> 2) * 16 + q * 4 + (p & 3);
        int slot = (wc * 16 + c) * 2;
        cv[row * 64 + slot]     = v1[p];  ci[row * 64 + slot]     = i1[p];
        cv[row * 64 + slot + 1] = v2[p];  ci[row * 64 + slot + 1] = i2[p];
    }
    __syncthreads();

    int* idx_fin = (int*)&B_sh[0][0];      // 128 ints, B_sh alias

    if (t < BN) {
        // coarse argmin over 64 slots (ties -> lowest index)
        float mv = 3.4e38f; int mi = 0x7fffffff;
#pragma unroll 8
        for (int s = 0; s < 64; ++s) {
            float v = cv[t * 64 + s]; int id = ci[t * 64 + s];
            if (v < mv || (v == mv && id < mi)) { mv = v; mi = id; }
        }
        // collect near-tie candidates
        int   cand[8]; int nc = 0;
        float thr = mv + MARGIN;
        for (int s = 0; s < 64; ++s) {
            float v = cv[t * 64 + s]; int id = ci[t * 64 + s];
            if (v <= thr && id < 1024 && nc < 8) cand[nc++] = id;
        }
        int final_id = mi;
        if (nc > 1) {
            // ---- bit-exact numpy-f32 rescore ----
            const float* zrow = z + (size_t)b_img * (256 * 4096) + (hw0 + t);
            float a_n = np_pw256_sq(zrow, 4096);      // np.sum(zf*zf, axis=1) bit-exact
            float best = 3.4e38f; int bid = 0x7fffffff;
            for (int cix = 0; cix < nc; ++cix) {
                int id = cand[cix];
                const float* er = emb + (size_t)id * 256;
                float b_k = np_pw256_sq(er, 1);       // np.sum(e*e, axis=1) bit-exact
                double cd = 0.0;
                for (int d = 0; d < 256; ++d)
                    cd = fma((double)zrow[(size_t)d * 4096], (double)er[d], cd);
                float c32 = (float)cd;                 // np einsum f32 (to ~2e-8)
                float sc  = __fsub_rn(__fadd_rn(a_n, b_k), __fmul_rn(2.0f, c32));
                if (sc < best || (sc == best && id < bid)) { best = sc; bid = id; }
            }
            final_id = bid;
        }
        idx_fin[t] = final_id;
        out[n0 + t] = (float)final_id;     // index output, f32
    }
    __syncthreads();

    // ---- z_q gather (pristine f32 emb) + coalesced NCHW f32 writes ----
    float* zq = out + 65536 + (size_t)b_img * (256 * 4096) + hw0;
#pragma unroll 2
    for (int it = 0; it < 32; ++it) {
        int task = it * 256 + t;   // 256 d x 32 quads
        int d = task >> 5;
        int o = task & 31;         // lane-contiguous -> coalesced stores
        f32x4 v;
#pragma unroll
        for (int j = 0; j < 4; ++j) {
            int id = idx_fin[o * 4 + j];
            v[j] = emb[(size_t)id * 256 + d];
        }
        *(f32x4*)&zq[(size_t)d * 4096 + o * 4] = v;
    }
}

// ---------------------------------------------------------------------------
extern "C" void kernel_launch(void* const* d_in, const int* in_sizes, int n_in,
                              void* d_out, int out_size, void* d_ws, size_t ws_size,
                              hipStream_t stream) {
    const float* z   = (const float*)d_in[0];   // f32 [16,256,64,64]
    const float* emb = (const float*)d_in[1];   // f32 [1024,256]
    unsigned short* embb = (unsigned short*)d_ws;  // 512 KB bf16 copy
    float* out = (float*)d_out;

    emb2bf16_kernel<<<256, 256, 0, stream>>>(emb, embb);
    vq_kernel<<<65536 / BN, 256, 0, stream>>>(z, emb, embb, out);
}

// Round 6
// 256.783 us; speedup vs baseline: 2.3176x; 2.3176x over previous
//
#include <hip/hip_runtime.h>
#include <hip/hip_bf16.h>
#include <stdint.h>
#include <stddef.h>

typedef __attribute__((ext_vector_type(4))) float f32x4;
typedef _Float16 f16x8 __attribute__((ext_vector_type(8)));

#define BN 128
// coarse scores are in 2^20-scaled units: sc = 2^20*(||e||^2 - 2 z.e) + eps.
// margin = (np grid ~6e-5 + >>8 sigma of fp16 coarse error ~6.4e-6) * 2^20
#define MARGIN 230.0f

// emb f32 [1024,256] -> fp16 bits of (e * 1024) in ws
__global__ __launch_bounds__(256) void emb2f16_kernel(const float* __restrict__ emb,
                                                      _Float16* __restrict__ embf) {
    int i = blockIdx.x * 256 + threadIdx.x;  // 65536 threads
#pragma unroll
    for (int j = 0; j < 4; ++j) {
        int k = i * 4 + j;
        embf[k] = (_Float16)(emb[k] * 1024.0f);   // *2^10 exact, then RNE cvt
    }
}

// ---------------------------------------------------------------------------
// B-chunk DMA: emb'[kt*128..+128][ds*32..+32] -> LDS [128 codes][4 slots][8]
// slot s of code k holds global grp g = s ^ (k&3)  (bank-conflict swizzle).
// global_load_lds width=16, wave-uniform base + lane*16.
// ---------------------------------------------------------------------------
__device__ __forceinline__ void prefetch_B(const _Float16* __restrict__ embf,
                                           _Float16* bbuf, int s, int w, int l) {
    int kt = s >> 3, ds = s & 7;
#pragma unroll
    for (int e = 0; e < 2; ++e) {
        int idx16 = (w * 2 + e) * 64 + l;  // 0..511 lane-contiguous
        int code  = idx16 >> 2;
        int slot  = idx16 & 3;
        int g     = slot ^ (code & 3);
        const _Float16* src = embf + (((size_t)(kt * 128 + code)) << 8) + ds * 32 + g * 8;
        void* dst = (void*)(bbuf + (size_t)idx16 * 8);
        __builtin_amdgcn_global_load_lds((const __attribute__((address_space(1))) void*)src,
                                         (__attribute__((address_space(3))) void*)dst,
                                         16, 0, 0);
    }
}

// ---------------------------------------------------------------------------
// Fused VQ: fp16 MFMA coarse pass (scaled score = e'norm - 2048*dot, best-2) +
// wave-cooperative bit-exact numpy-f32 rescore of near-tie rows via worklist.
// ---------------------------------------------------------------------------
__global__ __launch_bounds__(256, 2) void vq_kernel(
        const float* __restrict__ z,
        const float* __restrict__ emb,
        const _Float16* __restrict__ embf,
        float* __restrict__ out) {

    __shared__ _Float16 A_sh[BN * 256];        // 64 KB fp16 z tile
    __shared__ _Float16 B_sh[2][BN * 32];      // 16 KB dbuf emb chunks

    const int t  = threadIdx.x;
    const int w  = t >> 6;
    const int l  = t & 63;
    const int c  = l & 15;   // MFMA N-lane
    const int q  = l >> 4;   // MFMA quad
    const int wr = w >> 1;   // spatial half
    const int wc = w & 1;    // code half

    const int n0    = blockIdx.x * BN;
    const int b_img = n0 >> 12;
    const int hw0   = n0 & 4095;
    const float* zb = z + (size_t)b_img * (256 * 4096) + hw0;

    // ---- Stage A: z NCHW f32 -> fp16 [n][d], transposed, swizzled ----
#pragma unroll
    for (int it = 0; it < 4; ++it) {
        int task = it * 256 + t;      // 32 nquad x 32 dgroups
        int nq = task & 31;           // lane-contiguous -> 512B coalesced
        int dg = task >> 5;
        const float* g = zb + (size_t)(dg * 8) * 4096 + nq * 4;
        f32x4 col[8];
#pragma unroll
        for (int j = 0; j < 8; ++j) col[j] = *(const f32x4*)(g + (size_t)j * 4096);
#pragma unroll
        for (int u = 0; u < 4; ++u) {
            int n = nq * 4 + u;
            f16x8 v;
#pragma unroll
            for (int j = 0; j < 8; ++j) v[j] = (_Float16)col[j][u];
            *(f16x8*)&A_sh[n * 256 + ((dg ^ (n & 7)) * 8)] = v;
        }
    }
    __syncthreads();

    prefetch_B(embf, &B_sh[0][0], 0, w, l);

    f32x4 acc[4][4];
    float en_acc[4];
    float v1[16], v2[16];
    int   i1[16], i2[16];
#pragma unroll
    for (int i = 0; i < 4; ++i)
#pragma unroll
        for (int j = 0; j < 4; ++j) acc[i][j] = (f32x4){0.f, 0.f, 0.f, 0.f};
#pragma unroll
    for (int j = 0; j < 4; ++j) en_acc[j] = 0.f;
#pragma unroll
    for (int p = 0; p < 16; ++p) { v1[p] = 3.4e38f; v2[p] = 3.4e38f; i1[p] = 0x7fffffff; i2[p] = 0x7fffffff; }

    for (int kt = 0; kt < 8; ++kt) {
#pragma unroll
        for (int ds = 0; ds < 8; ++ds) {
            int s = kt * 8 + ds;
            __syncthreads();                                   // drains prefetch(s)
            if (s + 1 < 64) prefetch_B(embf, &B_sh[(s + 1) & 1][0], s + 1, w, l);

            const _Float16* Bb = &B_sh[s & 1][0];

            f16x8 af[4], bfr[4];
#pragma unroll
            for (int i = 0; i < 4; ++i) {
                int n  = wr * 64 + i * 16 + c;
                int pg = ((ds << 2) + q) ^ (n & 7);
                af[i] = *(const f16x8*)&A_sh[n * 256 + pg * 8];
            }
#pragma unroll
            for (int j = 0; j < 4; ++j) {
                int k = wc * 64 + j * 16 + c;
                bfr[j] = *(const f16x8*)&Bb[k * 32 + ((q ^ (k & 3)) * 8)];
            }
            // coarse e'-norm partials from the loaded fragments
#pragma unroll
            for (int j = 0; j < 4; ++j) {
                float sj = en_acc[j];
#pragma unroll
                for (int e = 0; e < 8; ++e) { float b = (float)bfr[j][e]; sj = fmaf(b, b, sj); }
                en_acc[j] = sj;
            }
#pragma unroll
            for (int i = 0; i < 4; ++i)
#pragma unroll
                for (int j = 0; j < 4; ++j)
                    acc[i][j] = __builtin_amdgcn_mfma_f32_16x16x32_f16(af[i], bfr[j], acc[i][j], 0, 0, 0);
        }

        // ---- kt epilogue: finish e'norm, scale-consistent score, best-2 ----
        // en = 2^20*||e||^2 ; acc = 2^10*(z.e)  =>  sc = en - 2048*acc
        //    = 2^20 * (||e||^2 - 2 z.e)   (argmin-equivalent, scale-consistent)
#pragma unroll
        for (int j = 0; j < 4; ++j) {
            float en = en_acc[j];
            en += __shfl_xor(en, 16, 64);
            en += __shfl_xor(en, 32, 64);
            en_acc[j] = 0.f;
            int code = kt * 128 + wc * 64 + j * 16 + c;
#pragma unroll
            for (int i = 0; i < 4; ++i) {
#pragma unroll
                for (int r = 0; r < 4; ++r) {
                    int p = i * 4 + r;
                    float sc = fmaf(-2048.0f, acc[i][j][r], en);
                    if (sc < v1[p]) {
                        v2[p] = v1[p]; i2[p] = i1[p];
                        v1[p] = sc;    i1[p] = code;
                    } else if (sc < v2[p]) {
                        v2[p] = sc;    i2[p] = code;
                    }
                }
            }
        }
#pragma unroll
        for (int i = 0; i < 4; ++i)
#pragma unroll
            for (int j = 0; j < 4; ++j) acc[i][j] = (f32x4){0.f, 0.f, 0.f, 0.f};
    }

    __syncthreads();   // A_sh/B_sh dead -> reuse as scratch

    // ---- dump best-2 per (lane,row), diagonal-swizzled: entry(slot,row) at
    //      [slot*128 + ((row+slot)&127)] -> scan reads stride-1, writes <=2-way
    float* cv = (float*)A_sh;              // 64 slots x 128 rows (32 KB)
    int*   ci = ((int*)A_sh) + 8192;       // 32 KB
    // worklist carved from B_sh (cap 128 = every row; no silent drop)
    int* idx_fin = (int*)&B_sh[0][0];      // 128
    int* wl_n    = idx_fin + 128;          // 1
    int* wl_row  = idx_fin + 129;          // 128
    int* wl_nc   = idx_fin + 257;          // 128
    int* wl_cand = idx_fin + 385;          // 128*8  (total 5636 B <= 16 KB)

    if (t == 0) wl_n[0] = 0;
#pragma unroll
    for (int p = 0; p < 16; ++p) {
        int row = wr * 64 + (p >> 2) * 16 + q * 4 + (p & 3);
        int s0  = (wc * 16 + c) * 2;
        cv[s0 * 128       + ((row + s0)     & 127)] = v1[p];
        ci[s0 * 128       + ((row + s0)     & 127)] = i1[p];
        cv[(s0 + 1) * 128 + ((row + s0 + 1) & 127)] = v2[p];
        ci[(s0 + 1) * 128 + ((row + s0 + 1) & 127)] = i2[p];
    }
    __syncthreads();

    if (t < BN) {
        float mv = 3.4e38f; int mi = 0x7fffffff;
#pragma unroll 8
        for (int s = 0; s < 64; ++s) {
            float v = cv[s * 128 + ((t + s) & 127)];
            int  id = ci[s * 128 + ((t + s) & 127)];
            if (v < mv || (v == mv && id < mi)) { mv = v; mi = id; }
        }
        int   cand[8]; int nc = 0;
        float thr = mv + MARGIN;
        for (int s = 0; s < 64; ++s) {
            float v = cv[s * 128 + ((t + s) & 127)];
            int  id = ci[s * 128 + ((t + s) & 127)];
            if (v <= thr && id < 1024 && nc < 8) cand[nc++] = id;
        }
        idx_fin[t] = mi;
        if (nc > 1) {
            int slot = atomicAdd(wl_n, 1);
            wl_row[slot] = t;
            wl_nc[slot]  = nc;
            for (int i = 0; i < nc; ++i) wl_cand[slot * 8 + i] = cand[i];
        }
    }
    __syncthreads();

    // ---- wave-cooperative bit-exact numpy-f32 rescore ----
    int nwl = wl_n[0];
    for (int e = w; e < nwl; e += 4) {
        int row = wl_row[e];
        int nc  = wl_nc[e];
        const float* zrow = zb + row;      // element d at zrow[d*4096]

        // a_n: np pairwise sum of z^2, 16 parallel chains (np 8-acc x 2 halves)
        int j  = l & 15, h = j >> 3, jj = j & 7;
        float x0 = zrow[(size_t)(h * 128 + jj) * 4096];
        float r  = __fmul_rn(x0, x0);
        for (int m = 1; m < 16; ++m) {
            float x = zrow[(size_t)(h * 128 + jj + 8 * m) * 4096];
            r = __fadd_rn(r, __fmul_rn(x, x));
        }
        float s1 = __fadd_rn(r,  __shfl_xor(r,  1, 64));
        float s2 = __fadd_rn(s1, __shfl_xor(s1, 2, 64));
        float s4 = __fadd_rn(s2, __shfl_xor(s2, 4, 64));
        float a_n = __fadd_rn(s4, __shfl_xor(s4, 8, 64));
        a_n = __shfl(a_n, 0, 64);

        float best = 3.4e38f; int bid = 0x7fffffff;
        for (int cx = 0; cx < nc; ++cx) {
            int id = wl_cand[e * 8 + cx];
            const float* er = emb + (size_t)id * 256;
            // b_k: same bit-exact np tree, contiguous reads
            float y0 = er[h * 128 + jj];
            float rb = __fmul_rn(y0, y0);
            for (int m = 1; m < 16; ++m) {
                float y = er[h * 128 + jj + 8 * m];
                rb = __fadd_rn(rb, __fmul_rn(y, y));
            }
            float b1 = __fadd_rn(rb, __shfl_xor(rb, 1, 64));
            float b2 = __fadd_rn(b1, __shfl_xor(b1, 2, 64));
            float b4 = __fadd_rn(b2, __shfl_xor(b2, 4, 64));
            float b_k = __fadd_rn(b4, __shfl_xor(b4, 8, 64));
            b_k = __shfl(b_k, 0, 64);
            // c: f64 dot, 64-lane butterfly (order-free, ~exact)
            double cd = 0.0;
#pragma unroll
            for (int u = 0; u < 4; ++u) {
                int d = l + u * 64;
                cd = fma((double)zrow[(size_t)d * 4096], (double)er[d], cd);
            }
#pragma unroll
            for (int off = 1; off < 64; off <<= 1) cd += __shfl_xor(cd, off, 64);
            float c32 = (float)cd;
            float sc  = __fsub_rn(__fadd_rn(a_n, b_k), __fmul_rn(2.0f, c32));
            if (sc < best || (sc == best && id < bid)) { best = sc; bid = id; }
        }
        if (l == 0) idx_fin[row] = bid;
    }
    __syncthreads();

    // ---- final index write + z_q gather, coalesced NCHW ----
    if (t < BN) out[n0 + t] = (float)idx_fin[t];

    float* zq = out + 65536 + (size_t)b_img * (256 * 4096) + hw0;
#pragma unroll 2
    for (int it = 0; it < 32; ++it) {
        int task = it * 256 + t;   // 256 d x 32 quads
        int d = task >> 5;
        int o = task & 31;         // lane-contiguous -> coalesced stores
        f32x4 v;
#pragma unroll
        for (int jj2 = 0; jj2 < 4; ++jj2) {
            int id = idx_fin[o * 4 + jj2];
            v[jj2] = emb[(size_t)id * 256 + d];
        }
        *(f32x4*)&zq[(size_t)d * 4096 + o * 4] = v;
    }
}

// ---------------------------------------------------------------------------
extern "C" void kernel_launch(void* const* d_in, const int* in_sizes, int n_in,
                              void* d_out, int out_size, void* d_ws, size_t ws_size,
                              hipStream_t stream) {
    const float* z   = (const float*)d_in[0];   // f32 [16,256,64,64]
    const float* emb = (const float*)d_in[1];   // f32 [1024,256]
    _Float16* embf = (_Float16*)d_ws;            // 512 KB fp16 copy (e*1024)
    float* out = (float*)d_out;

    emb2f16_kernel<<<256, 256, 0, stream>>>(emb, embf);
    vq_kernel<<<65536 / BN, 256, 0, stream>>>(z, emb, embf, out);
}